// Round 2
// baseline (4994.288 us; speedup 1.0000x reference)
//
#include <hip/hip_runtime.h>

#define T_SAVE 128
#define D_DIM 32
#define BT 16
#define NTHREADS 512

typedef __attribute__((ext_vector_type(8))) short short8;
typedef __attribute__((ext_vector_type(4))) float f32x4;
typedef unsigned int uint32;

// one-time weight convert: RTN-even
__device__ __forceinline__ short f2bf(float x) {
    union { float f; unsigned u; } v; v.f = x;
    return (short)((v.u + 0x7fffu + ((v.u >> 16) & 1u)) >> 16);
}

// fast path: round-half-up both, pack hi16(lo)|hi16(hi) via v_perm_b32
__device__ __forceinline__ uint32 pack_bf2(float lo, float hi) {
    union { float f; uint32 u; } a, b; a.f = lo; b.f = hi;
    // combined bytes {src0[4..7], src1[0..3]}; take src1 bytes 2,3 then src0 bytes 2,3
    return __builtin_amdgcn_perm(b.u + 0x8000u, a.u + 0x8000u, 0x07060302u);
}

__device__ __forceinline__ float softplus_f(float x) {
    return fmaxf(x, 0.0f) + __logf(1.0f + __expf(-fabsf(x)));
}

static __device__ const float TA[5][5] = {
    {0.161f, 0.f, 0.f, 0.f, 0.f},
    {-0.008480655492356989f, 0.335480655492357f, 0.f, 0.f, 0.f},
    {2.8971530571054935f, -6.359448489975075f, 4.3622954328695815f, 0.f, 0.f},
    {5.325864828439257f, -11.748883564062828f, 7.4955393428898365f, -0.09249506636175525f, 0.f},
    {5.86145544294642f, -12.92096931784711f, 8.159367898576159f, -0.071584973281401f, -0.028269050394068383f}
};

__global__ __launch_bounds__(NTHREADS, 2)
void node_mfma(const float* __restrict__ ts, const float* __restrict__ y0,
               const float* __restrict__ Win, const float* __restrict__ bin,
               const float* __restrict__ Wh, const float* __restrict__ bh,
               const float* __restrict__ Wout, const float* __restrict__ bout,
               float* __restrict__ out)
{
    __shared__ __align__(16) float sy[BT][36];       // fp32 state [sample][dim]
    __shared__ __align__(16) float sk[6][BT][36];    // fp32 stage k's [st][sample][dim]
    __shared__ __align__(16) short sha[BT * 136];    // bf16 act [sample][feature], stride 136
    __shared__ __align__(16) short shb[BT * 136];
    __shared__ float sts[T_SAVE];

    const int tid  = threadIdx.x;
    const int wave = tid >> 6;
    const int lane = tid & 63;
    const int n    = lane & 15;      // A-row (weight/feature row) AND D-col (sample)
    const int q    = lane >> 4;      // A/B k = 8q+j ; D rows = 4q+reg
    const int r    = 16 * wave + n;  // this wave's feature-row group
    const int fb   = 16 * wave + 4 * q;  // feature base this lane's D rows cover
    const int s0   = blockIdx.x * BT;

    // ---- weights as MFMA A-operand fragments (A[m=row][k], k-contig — same lane map as B) ----
    short8 winf;
    short8 whf[2][4];
    short8 woutf[4] = {};
    #pragma unroll
    for (int j = 0; j < 8; ++j) winf[j] = f2bf(Win[r * 32 + 8 * q + j]);
    #pragma unroll
    for (int L = 0; L < 2; ++L)
        #pragma unroll
        for (int c = 0; c < 4; ++c)
            #pragma unroll
            for (int j = 0; j < 8; ++j)
                whf[L][c][j] = f2bf(Wh[L * 16384 + r * 128 + 32 * c + 8 * q + j]);
    float bout4[4] = {0.f, 0.f, 0.f, 0.f};
    if (wave < 2) {
        #pragma unroll
        for (int c = 0; c < 4; ++c)
            #pragma unroll
            for (int j = 0; j < 8; ++j)
                woutf[c][j] = f2bf(Wout[r * 128 + 32 * c + 8 * q + j]);
        #pragma unroll
        for (int rr = 0; rr < 4; ++rr) bout4[rr] = bout[fb + rr];
    }
    float bin4[4], bh04[4], bh14[4];
    #pragma unroll
    for (int rr = 0; rr < 4; ++rr) {
        bin4[rr] = bin[fb + rr];
        bh04[rr] = bh[fb + rr];
        bh14[rr] = bh[128 + fb + rr];
    }

    // ---- init ----
    {
        const int s = tid >> 5, d = tid & 31;
        float v = y0[(s0 + s) * D_DIM + d];
        sy[s][d] = v;
        out[(size_t)(s0 + s) * (T_SAVE * D_DIM) + d] = v;
    }
    if (tid < T_SAVE) sts[tid] = ts[tid];
    __syncthreads();

    // hidden layer: D[feat][sample] = mfma(Wfrag, act_frag); pack 4 bf16 -> one b64 store
    auto hidden = [&](const short* src, short* dst, const short8* wf, const float* bias4) {
        f32x4 acc = {0.f, 0.f, 0.f, 0.f};
        #pragma unroll
        for (int c = 0; c < 4; ++c) {
            short8 b = *(const short8*)(src + n * 136 + 32 * c + 8 * q);
            acc = __builtin_amdgcn_mfma_f32_16x16x32_bf16(wf[c], b, acc, 0, 0, 0);
        }
        float v0 = softplus_f(acc[0] + bias4[0]);
        float v1 = softplus_f(acc[1] + bias4[1]);
        float v2 = softplus_f(acc[2] + bias4[2]);
        float v3 = softplus_f(acc[3] + bias4[3]);
        uint2 pk; pk.x = pack_bf2(v0, v1); pk.y = pack_bf2(v2, v3);
        *(uint2*)(dst + n * 136 + fb) = pk;   // sample n, features fb..fb+3
        __syncthreads();
    };

    for (int ti = 0; ti < T_SAVE - 1; ++ti) {
        const float hsub = (sts[ti + 1] - sts[ti]) * 0.25f;
        #pragma unroll 1
        for (int sub = 0; sub < 4; ++sub) {
            #pragma unroll
            for (int st = 0; st < 6; ++st) {
                // ---- build stage-y B-fragment: y + h*sum(TA*k), fp32x4 math ----
                f32x4 va = *(const f32x4*)&sy[n][8 * q];
                f32x4 vb = *(const f32x4*)&sy[n][8 * q + 4];
                #pragma unroll
                for (int jj = 0; jj < 5; ++jj) {
                    if (jj < st) {
                        const float c = hsub * TA[st - 1][jj];
                        va += c * *(const f32x4*)&sk[jj][n][8 * q];
                        vb += c * *(const f32x4*)&sk[jj][n][8 * q + 4];
                    }
                }
                union { short8 s8; uint32 u[4]; } af;
                af.u[0] = pack_bf2(va[0], va[1]);
                af.u[1] = pack_bf2(va[2], va[3]);
                af.u[2] = pack_bf2(vb[0], vb[1]);
                af.u[3] = pack_bf2(vb[2], vb[3]);

                // ---- input layer: D[feat][sample] ----
                f32x4 acc = {0.f, 0.f, 0.f, 0.f};
                acc = __builtin_amdgcn_mfma_f32_16x16x32_bf16(winf, af.s8, acc, 0, 0, 0);
                {
                    float v0 = softplus_f(acc[0] + bin4[0]);
                    float v1 = softplus_f(acc[1] + bin4[1]);
                    float v2 = softplus_f(acc[2] + bin4[2]);
                    float v3 = softplus_f(acc[3] + bin4[3]);
                    uint2 pk; pk.x = pack_bf2(v0, v1); pk.y = pack_bf2(v2, v3);
                    *(uint2*)(sha + n * 136 + fb) = pk;
                }
                __syncthreads();

                hidden(sha, shb, whf[0], bh04);  // h1
                hidden(shb, sha, whf[1], bh14);  // h2

                // ---- output layer: waves 0,1 -> k_st fp32, one b128 store ----
                if (wave < 2) {
                    f32x4 oc = {0.f, 0.f, 0.f, 0.f};
                    #pragma unroll
                    for (int c = 0; c < 4; ++c) {
                        short8 b = *(const short8*)(sha + n * 136 + 32 * c + 8 * q);
                        oc = __builtin_amdgcn_mfma_f32_16x16x32_bf16(woutf[c], b, oc, 0, 0, 0);
                    }
                    oc[0] += bout4[0]; oc[1] += bout4[1];
                    oc[2] += bout4[2]; oc[3] += bout4[3];
                    *(f32x4*)&sk[st][n][fb] = oc;   // sample n, dims fb..fb+3
                }
                __syncthreads();
            }
            // ---- Tsit5 combine ----
            {
                const int s = tid >> 5, d = tid & 31;
                float yv = sy[s][d];
                yv += hsub * (0.09646076681806523f  * sk[0][s][d]
                            + 0.01f                 * sk[1][s][d]
                            + 0.4798896504144996f   * sk[2][s][d]
                            + 1.379008574103742f    * sk[3][s][d]
                            + (-3.290069515436081f) * sk[4][s][d]
                            + 2.324710524099774f    * sk[5][s][d]);
                sy[s][d] = yv;
            }
            __syncthreads();
        }
        // ---- save point ----
        {
            const int s = tid >> 5, d = tid & 31;
            out[(size_t)(s0 + s) * (T_SAVE * D_DIM) + (ti + 1) * D_DIM + d] = sy[s][d];
        }
    }
}

extern "C" void kernel_launch(void* const* d_in, const int* in_sizes, int n_in,
                              void* d_out, int out_size, void* d_ws, size_t ws_size,
                              hipStream_t stream) {
    const float* ts   = (const float*)d_in[0];
    const float* y0   = (const float*)d_in[1];
    const float* Win  = (const float*)d_in[2];
    const float* bin  = (const float*)d_in[3];
    const float* Wh   = (const float*)d_in[4];
    const float* bh   = (const float*)d_in[5];
    const float* Wout = (const float*)d_in[6];
    const float* bout = (const float*)d_in[7];
    float* out = (float*)d_out;

    const int Btot = in_sizes[1] / D_DIM;  // 4096
    dim3 grid(Btot / BT), block(NTHREADS);
    node_mfma<<<grid, block, 0, stream>>>(ts, y0, Win, bin, Wh, bh, Wout, bout, out);
}

// Round 3
// 4759.715 us; speedup vs baseline: 1.0493x; 1.0493x over previous
//
#include <hip/hip_runtime.h>

#define T_SAVE 128
#define NTH 512

typedef __attribute__((ext_vector_type(8))) short short8;
typedef __attribute__((ext_vector_type(4))) float f32x4;
typedef unsigned int uint32;

// one-time weight convert: RTN-even
__device__ __forceinline__ short f2bf(float x) {
    union { float f; unsigned u; } v; v.f = x;
    return (short)((v.u + 0x7fffu + ((v.u >> 16) & 1u)) >> 16);
}
// fast activation path: round-half-up both halves, pack via v_perm_b32
__device__ __forceinline__ uint32 pack_bf2(float lo, float hi) {
    union { float f; uint32 u; } a, b; a.f = lo; b.f = hi;
    return __builtin_amdgcn_perm(b.u + 0x8000u, a.u + 0x8000u, 0x07060302u);
}
__device__ __forceinline__ float softplus_f(float x) {
    return fmaxf(x, 0.0f) + __logf(1.0f + __expf(-fabsf(x)));
}

static __device__ const float TA[5][5] = {
    {0.161f, 0.f, 0.f, 0.f, 0.f},
    {-0.008480655492356989f, 0.335480655492357f, 0.f, 0.f, 0.f},
    {2.8971530571054935f, -6.359448489975075f, 4.3622954328695815f, 0.f, 0.f},
    {5.325864828439257f, -11.748883564062828f, 7.4955393428898365f, -0.09249506636175525f, 0.f},
    {5.86145544294642f, -12.92096931784711f, 8.159367898576159f, -0.071584973281401f, -0.028269050394068383f}
};

__global__ __launch_bounds__(NTH, 2)
void node_mfma(const float* __restrict__ ts, const float* __restrict__ y0,
               const float* __restrict__ Win, const float* __restrict__ bin,
               const float* __restrict__ Wh, const float* __restrict__ bh,
               const float* __restrict__ Wout, const float* __restrict__ bout,
               float* __restrict__ out)
{
    // 3 rotating bf16 activation buffers [sample][feature], stride 136
    __shared__ __align__(16) short actA[16 * 136];
    __shared__ __align__(16) short actB[16 * 136];
    __shared__ __align__(16) short actC[16 * 136];
    // per-wave transpose scratch: 16 rows x 20 floats (80B stride: bank-clean, 16B-aligned)
    __shared__ __align__(16) float scr[8][320];

    const int tid  = threadIdx.x;
    const int wave = tid >> 6;
    const int lane = tid & 63;
    const int n    = lane & 15;          // sample within tile / A-row m
    const int q    = lane >> 4;          // quad
    const int r    = 16 * wave + n;      // this wave's feature row
    const int fb   = 16 * wave + 4 * q;  // feature base of this lane's D rows
    const int s0   = blockIdx.x * 16;

    // ---- weights as MFMA A-operand fragments: A[m=lane&15][k=8q+j] ----
    short8 winf, whf0[4], whf1[4], wo0[4], wo1[4];
    #pragma unroll
    for (int j = 0; j < 8; ++j) winf[j] = f2bf(Win[r * 32 + 8 * q + j]);
    #pragma unroll
    for (int c = 0; c < 4; ++c)
        #pragma unroll
        for (int j = 0; j < 8; ++j) {
            whf0[c][j] = f2bf(Wh[r * 128 + 32 * c + 8 * q + j]);
            whf1[c][j] = f2bf(Wh[16384 + r * 128 + 32 * c + 8 * q + j]);
            wo0[c][j]  = f2bf(Wout[n * 128 + 32 * c + 8 * q + j]);          // dims 0..15
            wo1[c][j]  = f2bf(Wout[(16 + n) * 128 + 32 * c + 8 * q + j]);   // dims 16..31
        }
    float bin4[4], bh04[4], bh14[4], boA[4], boB[4];
    #pragma unroll
    for (int rr = 0; rr < 4; ++rr) {
        bin4[rr] = bin[fb + rr];
        bh04[rr] = bh[fb + rr];
        bh14[rr] = bh[128 + fb + rr];
        boA[rr]  = bout[4 * q + rr];
        boB[rr]  = bout[16 + 4 * q + rr];
    }

    // ---- y state in registers (replicated per wave): yv[rr]=dim 4q+rr, yv[4+rr]=dim 16+4q+rr of sample n ----
    float yv[8];
    {
        f32x4 a = *(const f32x4*)&y0[(s0 + n) * 32 + 4 * q];
        f32x4 b = *(const f32x4*)&y0[(s0 + n) * 32 + 16 + 4 * q];
        #pragma unroll
        for (int rr = 0; rr < 4; ++rr) { yv[rr] = a[rr]; yv[4 + rr] = b[rr]; }
        if (wave == 0) {
            *(f32x4*)&out[(size_t)(s0 + n) * 4096 + 4 * q] = a;
            *(f32x4*)&out[(size_t)(s0 + n) * 4096 + 16 + 4 * q] = b;
        }
    }

    float kv[6][8];
    float* myscr = scr[wave];

    for (int ti = 0; ti < T_SAVE - 1; ++ti) {
        const float hsub = (ts[ti + 1] - ts[ti]) * 0.25f;
        #pragma unroll 1
        for (int sub = 0; sub < 4; ++sub) {
            #pragma unroll
            for (int st = 0; st < 6; ++st) {
                // ---- stage-y build (registers, replicated) ----
                float v[8];
                #pragma unroll
                for (int x = 0; x < 8; ++x) v[x] = yv[x];
                #pragma unroll
                for (int jj = 0; jj < 5; ++jj)
                    if (jj < st) {
                        const float c = hsub * TA[st - 1][jj];
                        #pragma unroll
                        for (int x = 0; x < 8; ++x) v[x] += c * kv[jj][x];
                    }
                // pack to bf16 dwords: {4q,4q+1},{4q+2,4q+3},{16+4q,..},{..}
                uint2 lo, hi;
                lo.x = pack_bf2(v[0], v[1]); lo.y = pack_bf2(v[2], v[3]);
                hi.x = pack_bf2(v[4], v[5]); hi.y = pack_bf2(v[6], v[7]);
                // wave-private transpose through LDS scratch (no barrier)
                *(uint2*)(myscr + n * 20 + 2 * q)     = lo;
                *(uint2*)(myscr + n * 20 + 8 + 2 * q) = hi;
                __asm__ volatile("s_waitcnt lgkmcnt(0)" ::: "memory");
                short8 bfrag = *(const short8*)((const short*)(myscr + n * 20 + 4 * q)); // dims 8q..8q+7, sample n

                // ---- input layer: feature rows 16w..16w+15 ----
                f32x4 acc = {0.f, 0.f, 0.f, 0.f};
                acc = __builtin_amdgcn_mfma_f32_16x16x32_bf16(winf, bfrag, acc, 0, 0, 0);
                {
                    float h0 = softplus_f(acc[0] + bin4[0]);
                    float h1 = softplus_f(acc[1] + bin4[1]);
                    float h2 = softplus_f(acc[2] + bin4[2]);
                    float h3 = softplus_f(acc[3] + bin4[3]);
                    uint2 pk; pk.x = pack_bf2(h0, h1); pk.y = pack_bf2(h2, h3);
                    *(uint2*)(actA + n * 136 + fb) = pk;
                }
                __syncthreads();  // B1

                // ---- hidden 1: actA -> actB ----
                {
                    f32x4 a2 = {0.f, 0.f, 0.f, 0.f};
                    #pragma unroll
                    for (int c = 0; c < 4; ++c) {
                        short8 b = *(const short8*)(actA + n * 136 + 32 * c + 8 * q);
                        a2 = __builtin_amdgcn_mfma_f32_16x16x32_bf16(whf0[c], b, a2, 0, 0, 0);
                    }
                    float h0 = softplus_f(a2[0] + bh04[0]);
                    float h1 = softplus_f(a2[1] + bh04[1]);
                    float h2 = softplus_f(a2[2] + bh04[2]);
                    float h3 = softplus_f(a2[3] + bh04[3]);
                    uint2 pk; pk.x = pack_bf2(h0, h1); pk.y = pack_bf2(h2, h3);
                    *(uint2*)(actB + n * 136 + fb) = pk;
                }
                __syncthreads();  // B2

                // ---- hidden 2: actB -> actC ----
                {
                    f32x4 a3 = {0.f, 0.f, 0.f, 0.f};
                    #pragma unroll
                    for (int c = 0; c < 4; ++c) {
                        short8 b = *(const short8*)(actB + n * 136 + 32 * c + 8 * q);
                        a3 = __builtin_amdgcn_mfma_f32_16x16x32_bf16(whf1[c], b, a3, 0, 0, 0);
                    }
                    float h0 = softplus_f(a3[0] + bh14[0]);
                    float h1 = softplus_f(a3[1] + bh14[1]);
                    float h2 = softplus_f(a3[2] + bh14[2]);
                    float h3 = softplus_f(a3[3] + bh14[3]);
                    uint2 pk; pk.x = pack_bf2(h0, h1); pk.y = pack_bf2(h2, h3);
                    *(uint2*)(actC + n * 136 + fb) = pk;
                }
                __syncthreads();  // B3

                // ---- output layer: every wave computes ALL 32 dims (redundant, barrier-free k) ----
                {
                    f32x4 k0 = {0.f, 0.f, 0.f, 0.f};
                    f32x4 k1 = {0.f, 0.f, 0.f, 0.f};
                    #pragma unroll
                    for (int c = 0; c < 4; ++c) {
                        short8 b = *(const short8*)(actC + n * 136 + 32 * c + 8 * q);
                        k0 = __builtin_amdgcn_mfma_f32_16x16x32_bf16(wo0[c], b, k0, 0, 0, 0);
                        k1 = __builtin_amdgcn_mfma_f32_16x16x32_bf16(wo1[c], b, k1, 0, 0, 0);
                    }
                    #pragma unroll
                    for (int rr = 0; rr < 4; ++rr) {
                        kv[st][rr]     = k0[rr] + boA[rr];
                        kv[st][4 + rr] = k1[rr] + boB[rr];
                    }
                }
            }
            // ---- Tsit5 combine (registers, replicated) ----
            #pragma unroll
            for (int x = 0; x < 8; ++x)
                yv[x] += hsub * (0.09646076681806523f  * kv[0][x]
                               + 0.01f                 * kv[1][x]
                               + 0.4798896504144996f   * kv[2][x]
                               + 1.379008574103742f    * kv[3][x]
                               + (-3.290069515436081f) * kv[4][x]
                               + 2.324710524099774f    * kv[5][x]);
        }
        // ---- save point (wave 0 only; all waves hold identical y) ----
        if (wave == 0) {
            f32x4 a, b;
            #pragma unroll
            for (int rr = 0; rr < 4; ++rr) { a[rr] = yv[rr]; b[rr] = yv[4 + rr]; }
            *(f32x4*)&out[(size_t)(s0 + n) * 4096 + (ti + 1) * 32 + 4 * q] = a;
            *(f32x4*)&out[(size_t)(s0 + n) * 4096 + (ti + 1) * 32 + 16 + 4 * q] = b;
        }
    }
}

extern "C" void kernel_launch(void* const* d_in, const int* in_sizes, int n_in,
                              void* d_out, int out_size, void* d_ws, size_t ws_size,
                              hipStream_t stream) {
    const float* ts   = (const float*)d_in[0];
    const float* y0   = (const float*)d_in[1];
    const float* Win  = (const float*)d_in[2];
    const float* bin  = (const float*)d_in[3];
    const float* Wh   = (const float*)d_in[4];
    const float* bh   = (const float*)d_in[5];
    const float* Wout = (const float*)d_in[6];
    const float* bout = (const float*)d_in[7];
    float* out = (float*)d_out;

    const int Btot = in_sizes[1] / 32;  // 4096 samples
    dim3 grid(Btot / 16), block(NTH);
    node_mfma<<<grid, block, 0, stream>>>(ts, y0, Win, bin, Wh, bh, Wout, bout, out);
}